// Round 9
// baseline (168.447 us; speedup 1.0000x reference)
//
#include <hip/hip_runtime.h>
#include <cstdint>

#define D_MODEL 1024
#define BATCH 4
#define SEQ 4096
#define M_TOT (BATCH*SEQ)   // 16384

#define BM 256
#define BNG 64              // per-gate N tile
#define BK 64
#define NKT (D_MODEL/BK)    // 16

#define XS_BYTES (BM*BK*2)                   // 32768
#define WG_BYTES (BNG*BK*2)                  // 8192 per gate
#define TILE_BYTES (XS_BYTES + 3*WG_BYTES)   // 57344
#define SMEM_BYTES (2*TILE_BYTES)            // 114688

#define NCHUNK 64
#define CHUNK 64

typedef __bf16 bf16x8 __attribute__((ext_vector_type(8)));
typedef float f32x4 __attribute__((ext_vector_type(4)));
typedef unsigned short u16x8 __attribute__((ext_vector_type(8)));

static __device__ __forceinline__ unsigned short f2bf(float f) {
    unsigned int u = __float_as_uint(f);
    return (unsigned short)((u + 0x7fffu + ((u >> 16) & 1u)) >> 16);
}
static __device__ __forceinline__ float ubf(unsigned short u) {
    return __uint_as_float((unsigned int)u << 16);
}

// ---------------- convert x (fp32 -> bf16), 8 elems/thread ----------------
__global__ void k_convert_x(const float* __restrict__ x, unsigned short* __restrict__ xb) {
    int i = blockIdx.x * 256 + threadIdx.x;
    const float4* p = (const float4*)x;
    float4 v0 = p[2*i], v1 = p[2*i+1];
    u16x8 r;
    r[0] = f2bf(v0.x); r[1] = f2bf(v0.y); r[2] = f2bf(v0.z); r[3] = f2bf(v0.w);
    r[4] = f2bf(v1.x); r[5] = f2bf(v1.y); r[6] = f2bf(v1.z); r[7] = f2bf(v1.w);
    *(u16x8*)(xb + (size_t)i * 8) = r;
}

// ---------------- transpose + convert W: wt[g][n][k] = W_g[k][n] ----------
__global__ void k_transpose_w(const float* __restrict__ Wf, const float* __restrict__ Wi,
                              const float* __restrict__ Wb, unsigned short* __restrict__ wt) {
    __shared__ float tile[32][33];
    int g = blockIdx.z;
    const float* W = (g == 0) ? Wf : (g == 1) ? Wi : Wb;
    int n0 = blockIdx.x * 32, k0 = blockIdx.y * 32;
    int tx = threadIdx.x, ty = threadIdx.y;   // 32 x 8
    for (int j = 0; j < 4; ++j)
        tile[ty + j*8][tx] = W[(size_t)(k0 + ty + j*8) * D_MODEL + n0 + tx];
    __syncthreads();
    for (int j = 0; j < 4; ++j) {
        int n = n0 + ty + j*8;
        wt[(size_t)g * D_MODEL * D_MODEL + (size_t)n * D_MODEL + k0 + tx] = f2bf(tile[tx][ty + j*8]);
    }
}

// ---------------- fused 3-gate GEMM, 256x(64x3) tile, 3-phase pipeline ----
#define GL16(gp, lp) \
    __builtin_amdgcn_global_load_lds((const __attribute__((address_space(1))) void*)(gp), \
                                     (__attribute__((address_space(3))) void*)(lp), 16, 0, 0)

__launch_bounds__(512)
__global__ void k_gemm_gates(const unsigned short* __restrict__ xb, const unsigned short* __restrict__ wt,
                             const float* __restrict__ bfv, const float* __restrict__ biv,
                             const float* __restrict__ bbv,
                             unsigned short* __restrict__ f_out, unsigned short* __restrict__ bg_out,
                             float* __restrict__ Ac, float* __restrict__ Bc) {
    extern __shared__ char smem[];
    const int tid  = threadIdx.x;
    const int wave = tid >> 6;            // 0..7
    const int lane = tid & 63;
    const int lr = lane & 15, lg = lane >> 4;
    // XCD-aware bijective swizzle (1024 % 8 == 0)
    const int bid = blockIdx.x;
    const int swz = (bid & 7) * 128 + (bid >> 3);
    const int mb = swz >> 4;              // 0..63
    const int nb = swz & 15;              // 0..15
    const int m0 = mb * BM;
    const int n0 = nb * BNG;
    const int wr = wave >> 2;             // 0..1 -> rows wr*128
    const int wc = wave & 3;              // 0..3 -> cols wc*16 per gate
    const int wrow = wr * 128;

    // ---- staging sources (A: 4 GL16 of 64 rows; B: 1 GL16 per gate) -----
    const int srow = tid >> 3;                               // 0..63
    const int scb  = ((tid & 7) * 16) ^ ((srow & 7) << 4);   // inverse-swizzled src col
    const unsigned short* sA0 = xb + (size_t)(m0 +   0 + srow) * D_MODEL + (scb >> 1);
    const unsigned short* sA1 = xb + (size_t)(m0 +  64 + srow) * D_MODEL + (scb >> 1);
    const unsigned short* sA2 = xb + (size_t)(m0 + 128 + srow) * D_MODEL + (scb >> 1);
    const unsigned short* sA3 = xb + (size_t)(m0 + 192 + srow) * D_MODEL + (scb >> 1);
    const unsigned short* sB0 = wt + 0ull*D_MODEL*D_MODEL + (size_t)(n0 + srow) * D_MODEL + (scb >> 1);
    const unsigned short* sB1 = wt + 1ull*D_MODEL*D_MODEL + (size_t)(n0 + srow) * D_MODEL + (scb >> 1);
    const unsigned short* sB2 = wt + 2ull*D_MODEL*D_MODEL + (size_t)(n0 + srow) * D_MODEL + (scb >> 1);

#define STAGE_A(db) do { char* _d = smem + (db)*TILE_BYTES + wave*1024; \
        GL16(sA0, _d + 0*8192); GL16(sA1, _d + 1*8192); \
        GL16(sA2, _d + 2*8192); GL16(sA3, _d + 3*8192); \
        sA0 += BK; sA1 += BK; sA2 += BK; sA3 += BK; } while (0)
#define STAGE_B01(db) do { char* _d = smem + (db)*TILE_BYTES + XS_BYTES + wave*1024; \
        GL16(sB0, _d + 0*8192); GL16(sB1, _d + 1*8192); \
        sB0 += BK; sB1 += BK; } while (0)
#define STAGE_B2(db) do { char* _d = smem + (db)*TILE_BYTES + XS_BYTES + 2*8192 + wave*1024; \
        GL16(sB2, _d); sB2 += BK; } while (0)

    f32x4 acc[3][8] = {};
    const int sxor = (lr & 7) << 4;

    // prologue: stage tile 0 (A x4, Bg01 x2, Bg2 x1); wait A+Bg01
    STAGE_A(0); STAGE_B01(0); STAGE_B2(0);
    asm volatile("s_waitcnt vmcnt(1)" ::: "memory");
    __builtin_amdgcn_s_barrier();

    bf16x8 af[2][4], af2[2][4], bw01[2][2], bw2[2];

#define READS_P1(tb) do { _Pragma("unroll") for (int kk = 0; kk < 2; ++kk) { \
        const int ko = (kk*64 + lg*16) ^ sxor; \
        _Pragma("unroll") for (int mi = 0; mi < 4; ++mi) \
            af[kk][mi] = *(const bf16x8*)((tb) + (wrow + mi*16 + lr)*128 + ko); \
        _Pragma("unroll") for (int g = 0; g < 2; ++g) \
            bw01[kk][g] = *(const bf16x8*)((tb) + XS_BYTES + g*WG_BYTES + (wc*16 + lr)*128 + ko); } } while (0)
#define READS_P2(tb) do { _Pragma("unroll") for (int kk = 0; kk < 2; ++kk) { \
        const int ko = (kk*64 + lg*16) ^ sxor; \
        _Pragma("unroll") for (int mi = 0; mi < 4; ++mi) \
            af2[kk][mi] = *(const bf16x8*)((tb) + (wrow + (mi+4)*16 + lr)*128 + ko); } } while (0)
#define READS_P3(tb) do { _Pragma("unroll") for (int kk = 0; kk < 2; ++kk) { \
        const int ko = (kk*64 + lg*16) ^ sxor; \
        bw2[kk] = *(const bf16x8*)((tb) + XS_BYTES + 2*WG_BYTES + (wc*16 + lr)*128 + ko); } } while (0)
#define MFMA_P1 do { _Pragma("unroll") for (int g = 0; g < 2; ++g) \
        _Pragma("unroll") for (int mi = 0; mi < 4; ++mi) \
        _Pragma("unroll") for (int kk = 0; kk < 2; ++kk) \
            acc[g][mi] = __builtin_amdgcn_mfma_f32_16x16x32_bf16(af[kk][mi], bw01[kk][g], acc[g][mi], 0,0,0); } while (0)
#define MFMA_P2 do { _Pragma("unroll") for (int g = 0; g < 2; ++g) \
        _Pragma("unroll") for (int mi = 0; mi < 4; ++mi) \
        _Pragma("unroll") for (int kk = 0; kk < 2; ++kk) \
            acc[g][mi+4] = __builtin_amdgcn_mfma_f32_16x16x32_bf16(af2[kk][mi], bw01[kk][g], acc[g][mi+4], 0,0,0); } while (0)
#define MFMA_P3 do { _Pragma("unroll") for (int mi = 0; mi < 4; ++mi) \
        _Pragma("unroll") for (int kk = 0; kk < 2; ++kk) { \
            acc[2][mi]   = __builtin_amdgcn_mfma_f32_16x16x32_bf16(af[kk][mi],  bw2[kk], acc[2][mi],   0,0,0); \
            acc[2][mi+4] = __builtin_amdgcn_mfma_f32_16x16x32_bf16(af2[kk][mi], bw2[kk], acc[2][mi+4], 0,0,0); } } while (0)
#define LGKM_FENCE do { asm volatile("s_waitcnt lgkmcnt(0)" ::: "memory"); \
        __builtin_amdgcn_sched_barrier(0); } while (0)

    #pragma unroll 1
    for (int kt = 0; kt < NKT - 1; ++kt) {
        const char* tb = smem + (kt & 1) * TILE_BYTES;
        const int db = (kt + 1) & 1;
        // P1: reads A0-3 + Bg01; stage A(kt+1)
        READS_P1(tb);
        STAGE_A(db);
        __builtin_amdgcn_s_barrier();
        LGKM_FENCE;
        __builtin_amdgcn_s_setprio(1); MFMA_P1; __builtin_amdgcn_s_setprio(0);
        __builtin_amdgcn_s_barrier();
        // P2: reads A4-7; stage Bg01(kt+1); wait for Bg2(kt)
        READS_P2(tb);
        STAGE_B01(db);
        asm volatile("s_waitcnt vmcnt(6)" ::: "memory");
        __builtin_amdgcn_s_barrier();
        LGKM_FENCE;
        __builtin_amdgcn_s_setprio(1); MFMA_P2; __builtin_amdgcn_s_setprio(0);
        __builtin_amdgcn_s_barrier();
        // P3: reads Bg2; stage Bg2(kt+1); wait for A(kt+1)+Bg01(kt+1)
        READS_P3(tb);
        STAGE_B2(db);
        asm volatile("s_waitcnt vmcnt(1)" ::: "memory");
        __builtin_amdgcn_s_barrier();
        LGKM_FENCE;
        __builtin_amdgcn_s_setprio(1); MFMA_P3; __builtin_amdgcn_s_setprio(0);
        __builtin_amdgcn_s_barrier();
    }
    { // peeled last tile (no stages)
        const char* tb = smem + ((NKT - 1) & 1) * TILE_BYTES;
        READS_P1(tb);
        __builtin_amdgcn_s_barrier();
        LGKM_FENCE;
        __builtin_amdgcn_s_setprio(1); MFMA_P1; __builtin_amdgcn_s_setprio(0);
        __builtin_amdgcn_s_barrier();
        READS_P2(tb);
        asm volatile("s_waitcnt vmcnt(0)" ::: "memory");  // Bg2 of last tile
        __builtin_amdgcn_s_barrier();
        LGKM_FENCE;
        __builtin_amdgcn_s_setprio(1); MFMA_P2; __builtin_amdgcn_s_setprio(0);
        __builtin_amdgcn_s_barrier();
        READS_P3(tb);
        LGKM_FENCE;
        __builtin_amdgcn_s_setprio(1); MFMA_P3; __builtin_amdgcn_s_setprio(0);
    }

    // ---- epilogue: gates -> bf16 f/bg + fused per-chunk aggregates -------
    // C/D: col = lane&15, row = (lane>>4)*4 + reg. Wave's 128 rows = 2
    // chunks (half = mi>>2); time idx within chunk = (mi&3)*16 + lg*4 + r.
    {
        const int col = n0 + wc*16 + lr;
        const float vbf = bfv[col], vbi = biv[col], vbb = bbv[col];
        float sA[2][4], sB[2][4];
        #pragma unroll
        for (int mi = 0; mi < 8; ++mi) {
            float Ap = 1.0f, Bp = 0.0f;
            #pragma unroll
            for (int r = 0; r < 4; ++r) {
                const int row = m0 + wrow + mi*16 + lg*4 + r;
                const float zf = acc[0][mi][r] + vbf;
                const float zi = acc[1][mi][r] + vbi;
                const float zb = (acc[2][mi][r] + vbb) * 0.03125f;  // /sqrt(1024)
                const float fg = 1.0f / (1.0f + __expf(-zf));
                const float ig = 1.0f / (1.0f + __expf(-zi));
                const unsigned short fu  = f2bf(fg);
                const unsigned short bgu = f2bf(ig * zb);
                const float a_r  = 1.0f - ubf(fu);
                const float bg_r = ubf(bgu);
                const size_t o = (size_t)row * D_MODEL + col;
                f_out[o]  = fu;
                bg_out[o] = bgu;
                Bp = fmaf(a_r, Bp, bg_r);
                Ap *= a_r;
            }
            sA[mi >> 2][mi & 3] = Ap;
            sB[mi >> 2][mi & 3] = Bp;
        }
        #pragma unroll
        for (int half = 0; half < 2; ++half) {
            float CA = 1.0f, CB = 0.0f;
            #pragma unroll
            for (int q = 0; q < 4; ++q) {
                float A = sA[half][q], B = sB[half][q];
                float Ao = __shfl_xor(A, 16), Bo = __shfl_xor(B, 16);
                float B1 = (lg & 1) ? fmaf(A, Bo, B) : fmaf(Ao, B, Bo);
                float A1 = A * Ao;
                Ao = __shfl_xor(A1, 32); Bo = __shfl_xor(B1, 32);
                float B2 = (lg & 2) ? fmaf(A1, Bo, B1) : fmaf(Ao, B1, Bo);
                float A2 = A1 * Ao;
                CB = fmaf(A2, CB, B2);
                CA = CA * A2;
            }
            if (lg == 0) {
                const int chG = mb * 4 + wr * 2 + half;   // global chunk id
                Ac[(size_t)chG * D_MODEL + col] = CA;
                Bc[(size_t)chG * D_MODEL + col] = CB;
            }
        }
    }
}

// ---------------- scan pass 2: exclusive prefix over chunks ---------------
__global__ void k_chunk_prefix(const float* __restrict__ Ac, const float* __restrict__ Bc,
                               float* __restrict__ H) {
    const int d = (blockIdx.x & 3) * 256 + threadIdx.x;
    const int b = blockIdx.x >> 2;
    float h = 0.0f;
    for (int c = 0; c < NCHUNK; ++c) {
        const size_t o = ((size_t)b * NCHUNK + c) * D_MODEL + d;
        H[o] = h;
        h = fmaf(Ac[o], h, Bc[o]);
    }
}

// ---------------- scan pass 3: apply (bf16 f/bg in, fp32 h out) -----------
__global__ void k_apply(const unsigned short* __restrict__ f, const unsigned short* __restrict__ bg,
                        const float* __restrict__ H, float* __restrict__ out) {
    const int d0 = (blockIdx.x & 1) * 512 + threadIdx.x * 2;
    const int c = (blockIdx.x >> 1) & 63;
    const int b = blockIdx.x >> 7;
    const size_t base = ((size_t)b * SEQ + (size_t)c * CHUNK) * D_MODEL + d0;
    const size_t hoff = ((size_t)b * NCHUNK + c) * D_MODEL + d0;
    float h0 = H[hoff], h1 = H[hoff + 1];
    for (int t = 0; t < CHUNK; ++t) {
        const size_t o = base + (size_t)t * D_MODEL;
        const unsigned int fv = *(const unsigned int*)(f + o);
        const unsigned int gv = *(const unsigned int*)(bg + o);
        const float a0 = 1.0f - __uint_as_float(fv << 16);
        const float a1 = 1.0f - __uint_as_float(fv & 0xffff0000u);
        const float b0 = __uint_as_float(gv << 16);
        const float b1 = __uint_as_float(gv & 0xffff0000u);
        h0 = fmaf(a0, h0, b0);
        h1 = fmaf(a1, h1, b1);
        *(float2*)(out + o) = make_float2(h0, h1);
    }
}

extern "C" void kernel_launch(void* const* d_in, const int* in_sizes, int n_in,
                              void* d_out, int out_size, void* d_ws, size_t ws_size,
                              hipStream_t stream) {
    const float* x   = (const float*)d_in[0];
    const float* Wf  = (const float*)d_in[1];
    const float* bfv = (const float*)d_in[2];
    const float* Wi  = (const float*)d_in[3];
    const float* biv = (const float*)d_in[4];
    const float* Wb  = (const float*)d_in[5];
    const float* bbv = (const float*)d_in[6];
    float* out = (float*)d_out;

    char* ws = (char*)d_ws;
    unsigned short* fbuf  = (unsigned short*)ws;                    // 0..32 MiB
    unsigned short* bgbuf = (unsigned short*)(ws + (32ull << 20));  // 32..64 MiB
    unsigned short* xb    = (unsigned short*)(ws + (64ull << 20));  // 64..96 MiB
    unsigned short* wt    = (unsigned short*)(ws + (96ull << 20));  // 96..102 MiB
    float* Ac = (float*)(ws + (102ull << 20));
    float* Bc = (float*)(ws + (103ull << 20));
    float* Hb = (float*)(ws + (64ull << 20));   // reuse xb region after GEMM

    hipFuncSetAttribute((const void*)k_gemm_gates,
                        hipFuncAttributeMaxDynamicSharedMemorySize, SMEM_BYTES);

    hipLaunchKernelGGL(k_convert_x, dim3((M_TOT * D_MODEL / 8) / 256), dim3(256), 0, stream, x, xb);
    hipLaunchKernelGGL(k_transpose_w, dim3(32, 32, 3), dim3(32, 8), 0, stream, Wf, Wi, Wb, wt);
    hipLaunchKernelGGL(k_gemm_gates, dim3((M_TOT / BM) * (D_MODEL / BNG)), dim3(512), SMEM_BYTES, stream,
                       xb, wt, bfv, biv, bbv, fbuf, bgbuf, Ac, Bc);
    hipLaunchKernelGGL(k_chunk_prefix, dim3(BATCH * (D_MODEL / 256)), dim3(256), 0, stream,
                       Ac, Bc, Hb);
    hipLaunchKernelGGL(k_apply, dim3(BATCH * NCHUNK * 2), dim3(256), 0, stream,
                       fbuf, bgbuf, Hb, out);
}

// Round 10
// 167.754 us; speedup vs baseline: 1.0041x; 1.0041x over previous
//
#include <hip/hip_runtime.h>
#include <cstdint>

#define D_MODEL 1024
#define BATCH 4
#define SEQ 4096
#define M_TOT (BATCH*SEQ)   // 16384

#define BM 256
#define BNG 64              // per-gate N tile
#define BK 64
#define NKT (D_MODEL/BK)    // 16

#define XS_BYTES (BM*BK*2)                   // 32768
#define WG_BYTES (BNG*BK*2)                  // 8192 per gate
#define TILE_BYTES (XS_BYTES + 3*WG_BYTES)   // 57344
#define SMEM_BYTES (2*TILE_BYTES)            // 114688

#define NCHUNK 64
#define CHUNK 64

typedef __bf16 bf16x8 __attribute__((ext_vector_type(8)));
typedef float f32x4 __attribute__((ext_vector_type(4)));
typedef unsigned short u16x8 __attribute__((ext_vector_type(8)));

static __device__ __forceinline__ unsigned short f2bf(float f) {
    unsigned int u = __float_as_uint(f);
    return (unsigned short)((u + 0x7fffu + ((u >> 16) & 1u)) >> 16);
}
static __device__ __forceinline__ float ubf(unsigned short u) {
    return __uint_as_float((unsigned int)u << 16);
}

// ---------------- convert x (fp32 -> bf16), 8 elems/thread ----------------
__global__ void k_convert_x(const float* __restrict__ x, unsigned short* __restrict__ xb) {
    int i = blockIdx.x * 256 + threadIdx.x;
    const float4* p = (const float4*)x;
    float4 v0 = p[2*i], v1 = p[2*i+1];
    u16x8 r;
    r[0] = f2bf(v0.x); r[1] = f2bf(v0.y); r[2] = f2bf(v0.z); r[3] = f2bf(v0.w);
    r[4] = f2bf(v1.x); r[5] = f2bf(v1.y); r[6] = f2bf(v1.z); r[7] = f2bf(v1.w);
    *(u16x8*)(xb + (size_t)i * 8) = r;
}

// ---------------- transpose + convert W: wt[g][n][k] = W_g[k][n] ----------
__global__ void k_transpose_w(const float* __restrict__ Wf, const float* __restrict__ Wi,
                              const float* __restrict__ Wb, unsigned short* __restrict__ wt) {
    __shared__ float tile[32][33];
    int g = blockIdx.z;
    const float* W = (g == 0) ? Wf : (g == 1) ? Wi : Wb;
    int n0 = blockIdx.x * 32, k0 = blockIdx.y * 32;
    int tx = threadIdx.x, ty = threadIdx.y;   // 32 x 8
    for (int j = 0; j < 4; ++j)
        tile[ty + j*8][tx] = W[(size_t)(k0 + ty + j*8) * D_MODEL + n0 + tx];
    __syncthreads();
    for (int j = 0; j < 4; ++j) {
        int n = n0 + ty + j*8;
        wt[(size_t)g * D_MODEL * D_MODEL + (size_t)n * D_MODEL + k0 + tx] = f2bf(tile[tx][ty + j*8]);
    }
}

// ---------------- fused 3-gate GEMM (256 x 64x3), compiler-scheduled ------
// Round-9 geometry (best bytes/FLOP, no spills) + round-8 scheduling style:
// no asm fences (they forced full lgkm drains and killed the compiler's
// fine-grained ds_read<->MFMA interleave), one barrier per K-tile, dbuf,
// STAGE(kt+1) issued before compute(kt). Fused gate+aggregate epilogue.
#define GL16(gp, lp) \
    __builtin_amdgcn_global_load_lds((const __attribute__((address_space(1))) void*)(gp), \
                                     (__attribute__((address_space(3))) void*)(lp), 16, 0, 0)

__launch_bounds__(512)
__global__ void k_gemm_gates(const unsigned short* __restrict__ xb, const unsigned short* __restrict__ wt,
                             const float* __restrict__ bfv, const float* __restrict__ biv,
                             const float* __restrict__ bbv,
                             unsigned short* __restrict__ f_out, unsigned short* __restrict__ bg_out,
                             float* __restrict__ Ac, float* __restrict__ Bc) {
    extern __shared__ char smem[];
    const int tid  = threadIdx.x;
    const int wave = tid >> 6;            // 0..7
    const int lane = tid & 63;
    const int lr = lane & 15, lg = lane >> 4;
    // XCD-aware bijective swizzle (1024 blocks % 8 == 0)
    const int bid = blockIdx.x;
    const int swz = (bid & 7) * 128 + (bid >> 3);
    const int mb = swz >> 4;              // 0..63
    const int nb = swz & 15;              // 0..15
    const int m0 = mb * BM;
    const int n0 = nb * BNG;
    const int wr = wave >> 2;             // 0..1 -> rows wr*128
    const int wc = wave & 3;              // 0..3 -> cols wc*16 per gate
    const int wrow = wr * 128;

    // ---- staging sources (7 GL16/thread-slot = 56 KiB/tile) --------------
    const int srow = tid >> 3;                               // 0..63
    const int scb  = ((tid & 7) * 16) ^ ((srow & 7) << 4);   // inverse-swizzled src col
    const unsigned short* sA0 = xb + (size_t)(m0 +   0 + srow) * D_MODEL + (scb >> 1);
    const unsigned short* sA1 = xb + (size_t)(m0 +  64 + srow) * D_MODEL + (scb >> 1);
    const unsigned short* sA2 = xb + (size_t)(m0 + 128 + srow) * D_MODEL + (scb >> 1);
    const unsigned short* sA3 = xb + (size_t)(m0 + 192 + srow) * D_MODEL + (scb >> 1);
    const unsigned short* sB0 = wt + 0ull*D_MODEL*D_MODEL + (size_t)(n0 + srow) * D_MODEL + (scb >> 1);
    const unsigned short* sB1 = wt + 1ull*D_MODEL*D_MODEL + (size_t)(n0 + srow) * D_MODEL + (scb >> 1);
    const unsigned short* sB2 = wt + 2ull*D_MODEL*D_MODEL + (size_t)(n0 + srow) * D_MODEL + (scb >> 1);

#define STAGE(db) do { \
        char* _d = smem + (db)*TILE_BYTES + wave*1024; \
        GL16(sA0, _d + 0*8192); GL16(sA1, _d + 1*8192); \
        GL16(sA2, _d + 2*8192); GL16(sA3, _d + 3*8192); \
        char* _e = _d + XS_BYTES; \
        GL16(sB0, _e + 0*8192); GL16(sB1, _e + 1*8192); GL16(sB2, _e + 2*8192); \
        sA0 += BK; sA1 += BK; sA2 += BK; sA3 += BK; \
        sB0 += BK; sB1 += BK; sB2 += BK; \
    } while (0)

    f32x4 acc[3][8] = {};
    const int sxor = (lr & 7) << 4;   // read-side swizzle (row&7 == lr&7)

    STAGE(0);
    __syncthreads();

    for (int kt = 0; kt < NKT; ++kt) {
        if (kt + 1 < NKT) STAGE((kt + 1) & 1);
        const char* tb = smem + (kt & 1) * TILE_BYTES;
        #pragma unroll
        for (int kk = 0; kk < 2; ++kk) {
            const int ko = (kk*64 + lg*16) ^ sxor;
            const int bro = (wc*16 + lr)*128 + ko;
            // small batch 1: 3 B-frags + 4 A-frags -> 12 MFMA
            bf16x8 bw0 = *(const bf16x8*)(tb + XS_BYTES + 0*WG_BYTES + bro);
            bf16x8 bw1 = *(const bf16x8*)(tb + XS_BYTES + 1*WG_BYTES + bro);
            bf16x8 bw2 = *(const bf16x8*)(tb + XS_BYTES + 2*WG_BYTES + bro);
            bf16x8 a0 = *(const bf16x8*)(tb + (wrow + 0*16 + lr)*128 + ko);
            bf16x8 a1 = *(const bf16x8*)(tb + (wrow + 1*16 + lr)*128 + ko);
            bf16x8 a2 = *(const bf16x8*)(tb + (wrow + 2*16 + lr)*128 + ko);
            bf16x8 a3 = *(const bf16x8*)(tb + (wrow + 3*16 + lr)*128 + ko);
            acc[0][0] = __builtin_amdgcn_mfma_f32_16x16x32_bf16(a0, bw0, acc[0][0], 0,0,0);
            acc[1][0] = __builtin_amdgcn_mfma_f32_16x16x32_bf16(a0, bw1, acc[1][0], 0,0,0);
            acc[2][0] = __builtin_amdgcn_mfma_f32_16x16x32_bf16(a0, bw2, acc[2][0], 0,0,0);
            acc[0][1] = __builtin_amdgcn_mfma_f32_16x16x32_bf16(a1, bw0, acc[0][1], 0,0,0);
            acc[1][1] = __builtin_amdgcn_mfma_f32_16x16x32_bf16(a1, bw1, acc[1][1], 0,0,0);
            acc[2][1] = __builtin_amdgcn_mfma_f32_16x16x32_bf16(a1, bw2, acc[2][1], 0,0,0);
            acc[0][2] = __builtin_amdgcn_mfma_f32_16x16x32_bf16(a2, bw0, acc[0][2], 0,0,0);
            acc[1][2] = __builtin_amdgcn_mfma_f32_16x16x32_bf16(a2, bw1, acc[1][2], 0,0,0);
            acc[2][2] = __builtin_amdgcn_mfma_f32_16x16x32_bf16(a2, bw2, acc[2][2], 0,0,0);
            acc[0][3] = __builtin_amdgcn_mfma_f32_16x16x32_bf16(a3, bw0, acc[0][3], 0,0,0);
            acc[1][3] = __builtin_amdgcn_mfma_f32_16x16x32_bf16(a3, bw1, acc[1][3], 0,0,0);
            acc[2][3] = __builtin_amdgcn_mfma_f32_16x16x32_bf16(a3, bw2, acc[2][3], 0,0,0);
            // small batch 2: 4 A-frags -> 12 MFMA
            bf16x8 a4 = *(const bf16x8*)(tb + (wrow + 4*16 + lr)*128 + ko);
            bf16x8 a5 = *(const bf16x8*)(tb + (wrow + 5*16 + lr)*128 + ko);
            bf16x8 a6 = *(const bf16x8*)(tb + (wrow + 6*16 + lr)*128 + ko);
            bf16x8 a7 = *(const bf16x8*)(tb + (wrow + 7*16 + lr)*128 + ko);
            acc[0][4] = __builtin_amdgcn_mfma_f32_16x16x32_bf16(a4, bw0, acc[0][4], 0,0,0);
            acc[1][4] = __builtin_amdgcn_mfma_f32_16x16x32_bf16(a4, bw1, acc[1][4], 0,0,0);
            acc[2][4] = __builtin_amdgcn_mfma_f32_16x16x32_bf16(a4, bw2, acc[2][4], 0,0,0);
            acc[0][5] = __builtin_amdgcn_mfma_f32_16x16x32_bf16(a5, bw0, acc[0][5], 0,0,0);
            acc[1][5] = __builtin_amdgcn_mfma_f32_16x16x32_bf16(a5, bw1, acc[1][5], 0,0,0);
            acc[2][5] = __builtin_amdgcn_mfma_f32_16x16x32_bf16(a5, bw2, acc[2][5], 0,0,0);
            acc[0][6] = __builtin_amdgcn_mfma_f32_16x16x32_bf16(a6, bw0, acc[0][6], 0,0,0);
            acc[1][6] = __builtin_amdgcn_mfma_f32_16x16x32_bf16(a6, bw1, acc[1][6], 0,0,0);
            acc[2][6] = __builtin_amdgcn_mfma_f32_16x16x32_bf16(a6, bw2, acc[2][6], 0,0,0);
            acc[0][7] = __builtin_amdgcn_mfma_f32_16x16x32_bf16(a7, bw0, acc[0][7], 0,0,0);
            acc[1][7] = __builtin_amdgcn_mfma_f32_16x16x32_bf16(a7, bw1, acc[1][7], 0,0,0);
            acc[2][7] = __builtin_amdgcn_mfma_f32_16x16x32_bf16(a7, bw2, acc[2][7], 0,0,0);
        }
        __syncthreads();   // drains stage; protects buffer reuse
    }

    // ---- epilogue: gates -> bf16 f/bg + fused per-chunk aggregates -------
    // C/D: col = lane&15, row = (lane>>4)*4 + reg. Wave's 128 rows = 2
    // chunks (half = mi>>2); time idx within chunk = (mi&3)*16 + lg*4 + r.
    {
        const int col = n0 + wc*16 + lr;
        const float vbf = bfv[col], vbi = biv[col], vbb = bbv[col];
        float sA[2][4], sB[2][4];
        #pragma unroll
        for (int mi = 0; mi < 8; ++mi) {
            float Ap = 1.0f, Bp = 0.0f;
            #pragma unroll
            for (int r = 0; r < 4; ++r) {
                const int row = m0 + wrow + mi*16 + lg*4 + r;
                const float zf = acc[0][mi][r] + vbf;
                const float zi = acc[1][mi][r] + vbi;
                const float zb = (acc[2][mi][r] + vbb) * 0.03125f;  // /sqrt(1024)
                const float fg = 1.0f / (1.0f + __expf(-zf));
                const float ig = 1.0f / (1.0f + __expf(-zi));
                const unsigned short fu  = f2bf(fg);
                const unsigned short bgu = f2bf(ig * zb);
                const float a_r  = 1.0f - ubf(fu);
                const float bg_r = ubf(bgu);
                const size_t o = (size_t)row * D_MODEL + col;
                f_out[o]  = fu;
                bg_out[o] = bgu;
                Bp = fmaf(a_r, Bp, bg_r);
                Ap *= a_r;
            }
            sA[mi >> 2][mi & 3] = Ap;
            sB[mi >> 2][mi & 3] = Bp;
        }
        #pragma unroll
        for (int half = 0; half < 2; ++half) {
            float CA = 1.0f, CB = 0.0f;
            #pragma unroll
            for (int q = 0; q < 4; ++q) {
                float A = sA[half][q], B = sB[half][q];
                float Ao = __shfl_xor(A, 16), Bo = __shfl_xor(B, 16);
                float B1 = (lg & 1) ? fmaf(A, Bo, B) : fmaf(Ao, B, Bo);
                float A1 = A * Ao;
                Ao = __shfl_xor(A1, 32); Bo = __shfl_xor(B1, 32);
                float B2 = (lg & 2) ? fmaf(A1, Bo, B1) : fmaf(Ao, B1, Bo);
                float A2 = A1 * Ao;
                CB = fmaf(A2, CB, B2);
                CA = CA * A2;
            }
            if (lg == 0) {
                const int chG = mb * 4 + wr * 2 + half;   // global chunk id
                Ac[(size_t)chG * D_MODEL + col] = CA;
                Bc[(size_t)chG * D_MODEL + col] = CB;
            }
        }
    }
#undef STAGE
}

// ---------------- scan pass 2: exclusive prefix over chunks ---------------
__global__ void k_chunk_prefix(const float* __restrict__ Ac, const float* __restrict__ Bc,
                               float* __restrict__ H) {
    const int d = (blockIdx.x & 3) * 256 + threadIdx.x;
    const int b = blockIdx.x >> 2;
    float h = 0.0f;
    for (int c = 0; c < NCHUNK; ++c) {
        const size_t o = ((size_t)b * NCHUNK + c) * D_MODEL + d;
        H[o] = h;
        h = fmaf(Ac[o], h, Bc[o]);
    }
}

// ---------------- scan pass 3: apply (bf16 f/bg in, fp32 h out) -----------
__global__ void k_apply(const unsigned short* __restrict__ f, const unsigned short* __restrict__ bg,
                        const float* __restrict__ H, float* __restrict__ out) {
    const int d0 = (blockIdx.x & 1) * 512 + threadIdx.x * 2;
    const int c = (blockIdx.x >> 1) & 63;
    const int b = blockIdx.x >> 7;
    const size_t base = ((size_t)b * SEQ + (size_t)c * CHUNK) * D_MODEL + d0;
    const size_t hoff = ((size_t)b * NCHUNK + c) * D_MODEL + d0;
    float h0 = H[hoff], h1 = H[hoff + 1];
    for (int t = 0; t < CHUNK; ++t) {
        const size_t o = base + (size_t)t * D_MODEL;
        const unsigned int fv = *(const unsigned int*)(f + o);
        const unsigned int gv = *(const unsigned int*)(bg + o);
        const float a0 = 1.0f - __uint_as_float(fv << 16);
        const float a1 = 1.0f - __uint_as_float(fv & 0xffff0000u);
        const float b0 = __uint_as_float(gv << 16);
        const float b1 = __uint_as_float(gv & 0xffff0000u);
        h0 = fmaf(a0, h0, b0);
        h1 = fmaf(a1, h1, b1);
        *(float2*)(out + o) = make_float2(h0, h1);
    }
}

extern "C" void kernel_launch(void* const* d_in, const int* in_sizes, int n_in,
                              void* d_out, int out_size, void* d_ws, size_t ws_size,
                              hipStream_t stream) {
    const float* x   = (const float*)d_in[0];
    const float* Wf  = (const float*)d_in[1];
    const float* bfv = (const float*)d_in[2];
    const float* Wi  = (const float*)d_in[3];
    const float* biv = (const float*)d_in[4];
    const float* Wb  = (const float*)d_in[5];
    const float* bbv = (const float*)d_in[6];
    float* out = (float*)d_out;

    char* ws = (char*)d_ws;
    unsigned short* fbuf  = (unsigned short*)ws;                    // 0..32 MiB
    unsigned short* bgbuf = (unsigned short*)(ws + (32ull << 20));  // 32..64 MiB
    unsigned short* xb    = (unsigned short*)(ws + (64ull << 20));  // 64..96 MiB
    unsigned short* wt    = (unsigned short*)(ws + (96ull << 20));  // 96..102 MiB
    float* Ac = (float*)(ws + (102ull << 20));
    float* Bc = (float*)(ws + (103ull << 20));
    float* Hb = (float*)(ws + (64ull << 20));   // reuse xb region after GEMM

    hipFuncSetAttribute((const void*)k_gemm_gates,
                        hipFuncAttributeMaxDynamicSharedMemorySize, SMEM_BYTES);

    hipLaunchKernelGGL(k_convert_x, dim3((M_TOT * D_MODEL / 8) / 256), dim3(256), 0, stream, x, xb);
    hipLaunchKernelGGL(k_transpose_w, dim3(32, 32, 3), dim3(32, 8), 0, stream, Wf, Wi, Wb, wt);
    hipLaunchKernelGGL(k_gemm_gates, dim3((M_TOT / BM) * (D_MODEL / BNG)), dim3(512), SMEM_BYTES, stream,
                       xb, wt, bfv, biv, bbv, fbuf, bgbuf, Ac, Bc);
    hipLaunchKernelGGL(k_chunk_prefix, dim3(BATCH * (D_MODEL / 256)), dim3(256), 0, stream,
                       Ac, Bc, Hb);
    hipLaunchKernelGGL(k_apply, dim3(BATCH * NCHUNK * 2), dim3(256), 0, stream,
                       fbuf, bgbuf, Hb, out);
}

// Round 11
// 167.488 us; speedup vs baseline: 1.0057x; 1.0016x over previous
//
#include <hip/hip_runtime.h>
#include <cstdint>

#define D_MODEL 1024
#define BATCH 4
#define SEQ 4096
#define M_TOT (BATCH*SEQ)   // 16384

#define BM 128
#define BNG 64              // per-gate N tile
#define BK 64
#define NKT (D_MODEL/BK)    // 16

#define XS_BYTES (BM*BK*2)                   // 16384
#define WG_BYTES (BNG*BK*2)                  // 8192 per gate
#define TILE_BYTES (XS_BYTES + 3*WG_BYTES)   // 40960
#define SMEM_BYTES (2*TILE_BYTES)            // 81920 -> 2 blocks/CU

#define NCHUNK 64
#define CHUNK 64

typedef __bf16 bf16x8 __attribute__((ext_vector_type(8)));
typedef float f32x4 __attribute__((ext_vector_type(4)));
typedef unsigned short u16x8 __attribute__((ext_vector_type(8)));

static __device__ __forceinline__ unsigned short f2bf(float f) {
    unsigned int u = __float_as_uint(f);
    return (unsigned short)((u + 0x7fffu + ((u >> 16) & 1u)) >> 16);
}
static __device__ __forceinline__ float ubf(unsigned short u) {
    return __uint_as_float((unsigned int)u << 16);
}

// ---------------- convert x (fp32 -> bf16), 8 elems/thread ----------------
__global__ void k_convert_x(const float* __restrict__ x, unsigned short* __restrict__ xb) {
    int i = blockIdx.x * 256 + threadIdx.x;
    const float4* p = (const float4*)x;
    float4 v0 = p[2*i], v1 = p[2*i+1];
    u16x8 r;
    r[0] = f2bf(v0.x); r[1] = f2bf(v0.y); r[2] = f2bf(v0.z); r[3] = f2bf(v0.w);
    r[4] = f2bf(v1.x); r[5] = f2bf(v1.y); r[6] = f2bf(v1.z); r[7] = f2bf(v1.w);
    *(u16x8*)(xb + (size_t)i * 8) = r;
}

// ---------------- transpose + convert W: wt[g][n][k] = W_g[k][n] ----------
__global__ void k_transpose_w(const float* __restrict__ Wf, const float* __restrict__ Wi,
                              const float* __restrict__ Wb, unsigned short* __restrict__ wt) {
    __shared__ float tile[32][33];
    int g = blockIdx.z;
    const float* W = (g == 0) ? Wf : (g == 1) ? Wi : Wb;
    int n0 = blockIdx.x * 32, k0 = blockIdx.y * 32;
    int tx = threadIdx.x, ty = threadIdx.y;   // 32 x 8
    for (int j = 0; j < 4; ++j)
        tile[ty + j*8][tx] = W[(size_t)(k0 + ty + j*8) * D_MODEL + n0 + tx];
    __syncthreads();
    for (int j = 0; j < 4; ++j) {
        int n = n0 + ty + j*8;
        wt[(size_t)g * D_MODEL * D_MODEL + (size_t)n * D_MODEL + k0 + tx] = f2bf(tile[tx][ty + j*8]);
    }
}

// ---------------- fused 3-gate GEMM: 2 independent dbuf blocks per CU -----
// 4 waves (2x2), wave tile 64x32 per gate; 40 KiB tile double-buffered =
// 80 KiB -> 2 blocks/CU (two independent barrier domains: one block's
// MFMA/ds_read fills the other's barrier-drain gaps, m114 mechanism).
// Round-8 loop style (STAGE-next at top, single __syncthreads, no fences).
#define GL16(gp, lp) \
    __builtin_amdgcn_global_load_lds((const __attribute__((address_space(1))) void*)(gp), \
                                     (__attribute__((address_space(3))) void*)(lp), 16, 0, 0)

__launch_bounds__(256, 2)
__global__ void k_gemm_gates(const unsigned short* __restrict__ xb, const unsigned short* __restrict__ wt,
                             const float* __restrict__ bfv, const float* __restrict__ biv,
                             const float* __restrict__ bbv,
                             unsigned int* __restrict__ fbg_out,
                             float* __restrict__ Ac, float* __restrict__ Bc) {
    extern __shared__ char smem[];
    const int tid  = threadIdx.x;
    const int wave = tid >> 6;            // 0..3
    const int lane = tid & 63;
    const int lr = lane & 15, lg = lane >> 4;
    // XCD-aware bijective swizzle (2048 blocks % 8 == 0)
    const int bid = blockIdx.x;
    const int swz = (bid & 7) * 256 + (bid >> 3);
    const int mb = swz >> 4;              // 0..127
    const int nb = swz & 15;              // 0..15
    const int m0 = mb * BM;
    const int n0 = nb * BNG;
    const int wr = wave >> 1;             // 0..1 -> rows wr*64
    const int wc = wave & 1;              // 0..1 -> cols wc*32 per gate
    const int wrow = wr * 64;
    const int wcol = wc * 32;

    // ---- staging: 10 GL16/thread-slot = 40 KiB/tile ----------------------
    const int srl = tid >> 3;                                // 0..31, srl&7 == (tid>>3)&7
    const int scb = ((tid & 7) * 16) ^ ((srl & 7) << 4);     // inverse-swizzled src col
    const unsigned short* sA  = xb + (size_t)(m0 + srl) * D_MODEL + (scb >> 1);
    const unsigned short* sB0 = wt + 0ull*D_MODEL*D_MODEL + (size_t)(n0 + srl) * D_MODEL + (scb >> 1);
    const unsigned short* sB1 = wt + 1ull*D_MODEL*D_MODEL + (size_t)(n0 + srl) * D_MODEL + (scb >> 1);
    const unsigned short* sB2 = wt + 2ull*D_MODEL*D_MODEL + (size_t)(n0 + srl) * D_MODEL + (scb >> 1);

#define STAGE(db) do { \
        char* _d = smem + (db)*TILE_BYTES + wave*1024; \
        GL16(sA + 0*32*D_MODEL, _d + 0*4096); \
        GL16(sA + 1*32*D_MODEL, _d + 1*4096); \
        GL16(sA + 2*32*D_MODEL, _d + 2*4096); \
        GL16(sA + 3*32*D_MODEL, _d + 3*4096); \
        char* _e = _d + XS_BYTES; \
        GL16(sB0,                _e + 0*4096); \
        GL16(sB0 + 32*D_MODEL,   _e + 1*4096); \
        GL16(sB1,                _e + 2*4096); \
        GL16(sB1 + 32*D_MODEL,   _e + 3*4096); \
        GL16(sB2,                _e + 4*4096); \
        GL16(sB2 + 32*D_MODEL,   _e + 5*4096); \
        sA += BK; sB0 += BK; sB1 += BK; sB2 += BK; \
    } while (0)

    f32x4 acc[3][4][2] = {};
    const int sxor = (lr & 7) << 4;   // read-side swizzle (row&7 == lr&7)

    STAGE(0);
    __syncthreads();

    for (int kt = 0; kt < NKT; ++kt) {
        if (kt + 1 < NKT) STAGE((kt + 1) & 1);
        const char* tb = smem + (kt & 1) * TILE_BYTES;
        #pragma unroll
        for (int kk = 0; kk < 2; ++kk) {
            const int ko = (kk*64 + lg*16) ^ sxor;
            bf16x8 bw[3][2];
            #pragma unroll
            for (int g = 0; g < 3; ++g)
                #pragma unroll
                for (int ni = 0; ni < 2; ++ni)
                    bw[g][ni] = *(const bf16x8*)(tb + XS_BYTES + g*WG_BYTES +
                                                 (wcol + ni*16 + lr)*128 + ko);
            bf16x8 af[4];
            #pragma unroll
            for (int mi = 0; mi < 4; ++mi)
                af[mi] = *(const bf16x8*)(tb + (wrow + mi*16 + lr)*128 + ko);
            #pragma unroll
            for (int g = 0; g < 3; ++g)
                #pragma unroll
                for (int mi = 0; mi < 4; ++mi)
                    #pragma unroll
                    for (int ni = 0; ni < 2; ++ni)
                        acc[g][mi][ni] = __builtin_amdgcn_mfma_f32_16x16x32_bf16(
                            af[mi], bw[g][ni], acc[g][mi][ni], 0, 0, 0);
        }
        __syncthreads();   // drains stage; next iter overwrites other buffer
    }

    // ---- epilogue: gates -> packed u32 (f | bg<<16) + chunk aggregates ---
    // C/D: col = lane&15, row = (lane>>4)*4 + reg. Wave's 64 rows = one
    // chunk; time idx = mi*16 + lg*4 + r. (round-8-verified tree)
    #pragma unroll
    for (int ni = 0; ni < 2; ++ni) {
        const int col = n0 + wcol + ni*16 + lr;
        const float vbf = bfv[col], vbi = biv[col], vbb = bbv[col];
        float qA[4], qB[4];
        #pragma unroll
        for (int mi = 0; mi < 4; ++mi) {
            float Ap = 1.0f, Bp = 0.0f;
            #pragma unroll
            for (int r = 0; r < 4; ++r) {
                const int row = m0 + wrow + mi*16 + lg*4 + r;
                const float zf = acc[0][mi][ni][r] + vbf;
                const float zi = acc[1][mi][ni][r] + vbi;
                const float zb = (acc[2][mi][ni][r] + vbb) * 0.03125f;  // /sqrt(1024)
                const float fg = 1.0f / (1.0f + __expf(-zf));
                const float ig = 1.0f / (1.0f + __expf(-zi));
                const unsigned short fu  = f2bf(fg);
                const unsigned short bgu = f2bf(ig * zb);
                const float a_r  = 1.0f - ubf(fu);    // rounded values so
                const float bg_r = ubf(bgu);          // aggregates match apply
                fbg_out[(size_t)row * D_MODEL + col] =
                    (unsigned int)fu | ((unsigned int)bgu << 16);
                Bp = fmaf(a_r, Bp, bg_r);   // time order: r ascending
                Ap *= a_r;
            }
            qA[mi] = Ap; qB[mi] = Bp;
        }
        // ordered 4-lane (lg) tree over 16-row quarters, serial compose
        float CA = 1.0f, CB = 0.0f;
        #pragma unroll
        for (int q = 0; q < 4; ++q) {
            float A = qA[q], B = qB[q];
            float Ao = __shfl_xor(A, 16), Bo = __shfl_xor(B, 16);
            float B1 = (lg & 1) ? fmaf(A, Bo, B) : fmaf(Ao, B, Bo);
            float A1 = A * Ao;
            Ao = __shfl_xor(A1, 32); Bo = __shfl_xor(B1, 32);
            float B2 = (lg & 2) ? fmaf(A1, Bo, B1) : fmaf(Ao, B1, Bo);
            float A2 = A1 * Ao;
            CB = fmaf(A2, CB, B2);
            CA = CA * A2;
        }
        if (lg == 0) {
            const int chG = mb * 2 + wr;     // global chunk id
            Ac[(size_t)chG * D_MODEL + col] = CA;
            Bc[(size_t)chG * D_MODEL + col] = CB;
        }
    }
#undef STAGE
}

// ---------------- scan pass 2: exclusive prefix over chunks ---------------
__global__ void k_chunk_prefix(const float* __restrict__ Ac, const float* __restrict__ Bc,
                               float* __restrict__ H) {
    const int d = (blockIdx.x & 3) * 256 + threadIdx.x;
    const int b = blockIdx.x >> 2;
    float h = 0.0f;
    for (int c = 0; c < NCHUNK; ++c) {
        const size_t o = ((size_t)b * NCHUNK + c) * D_MODEL + d;
        H[o] = h;
        h = fmaf(Ac[o], h, Bc[o]);
    }
}

// ---------------- scan pass 3: apply (packed u32 in, fp32 h out) ----------
__global__ void k_apply(const unsigned int* __restrict__ fbg,
                        const float* __restrict__ H, float* __restrict__ out) {
    const int d0 = (blockIdx.x & 1) * 512 + threadIdx.x * 2;
    const int c = (blockIdx.x >> 1) & 63;
    const int b = blockIdx.x >> 7;
    const size_t base = ((size_t)b * SEQ + (size_t)c * CHUNK) * D_MODEL + d0;
    const size_t hoff = ((size_t)b * NCHUNK + c) * D_MODEL + d0;
    float h0 = H[hoff], h1 = H[hoff + 1];
    for (int t = 0; t < CHUNK; ++t) {
        const size_t o = base + (size_t)t * D_MODEL;
        const uint2 v = *(const uint2*)(fbg + o);
        const float a0 = 1.0f - __uint_as_float(v.x << 16);
        const float b0 = __uint_as_float(v.x & 0xffff0000u);
        const float a1 = 1.0f - __uint_as_float(v.y << 16);
        const float b1 = __uint_as_float(v.y & 0xffff0000u);
        h0 = fmaf(a0, h0, b0);
        h1 = fmaf(a1, h1, b1);
        *(float2*)(out + o) = make_float2(h0, h1);
    }
}

extern "C" void kernel_launch(void* const* d_in, const int* in_sizes, int n_in,
                              void* d_out, int out_size, void* d_ws, size_t ws_size,
                              hipStream_t stream) {
    const float* x   = (const float*)d_in[0];
    const float* Wf  = (const float*)d_in[1];
    const float* bfv = (const float*)d_in[2];
    const float* Wi  = (const float*)d_in[3];
    const float* biv = (const float*)d_in[4];
    const float* Wb  = (const float*)d_in[5];
    const float* bbv = (const float*)d_in[6];
    float* out = (float*)d_out;

    char* ws = (char*)d_ws;
    unsigned int*   fbg   = (unsigned int*)ws;                      // 0..64 MiB
    unsigned short* xb    = (unsigned short*)(ws + (64ull << 20));  // 64..96 MiB
    unsigned short* wt    = (unsigned short*)(ws + (96ull << 20));  // 96..102 MiB
    float* Ac = (float*)(ws + (102ull << 20));
    float* Bc = (float*)(ws + (103ull << 20));
    float* Hb = (float*)(ws + (64ull << 20));   // reuse xb region after GEMM

    hipFuncSetAttribute((const void*)k_gemm_gates,
                        hipFuncAttributeMaxDynamicSharedMemorySize, SMEM_BYTES);

    hipLaunchKernelGGL(k_convert_x, dim3((M_TOT * D_MODEL / 8) / 256), dim3(256), 0, stream, x, xb);
    hipLaunchKernelGGL(k_transpose_w, dim3(32, 32, 3), dim3(32, 8), 0, stream, Wf, Wi, Wb, wt);
    hipLaunchKernelGGL(k_gemm_gates, dim3((M_TOT / BM) * (D_MODEL / BNG)), dim3(256), SMEM_BYTES, stream,
                       xb, wt, bfv, biv, bbv, fbg, Ac, Bc);
    hipLaunchKernelGGL(k_chunk_prefix, dim3(BATCH * (D_MODEL / 256)), dim3(256), 0, stream,
                       Ac, Bc, Hb);
    hipLaunchKernelGGL(k_apply, dim3(BATCH * NCHUNK * 2), dim3(256), 0, stream,
                       fbg, Hb, out);
}

// Round 12
// 160.192 us; speedup vs baseline: 1.0515x; 1.0455x over previous
//
#include <hip/hip_runtime.h>
#include <cstdint>

#define D_MODEL 1024
#define BATCH 4
#define SEQ 4096
#define M_TOT (BATCH*SEQ)   // 16384

#define BM 128
#define BNG 64              // per-gate N tile
#define BK 64
#define NKT (D_MODEL/BK)    // 16

#define XS_BYTES (BM*BK*2)                   // 16384
#define WG_BYTES (BNG*BK*2)                  // 8192 per gate
#define TILE_BYTES (XS_BYTES + 3*WG_BYTES)   // 40960
#define SMEM_BYTES (2*TILE_BYTES)            // 81920 -> 2 blocks/CU

#define NCHUNK 64
#define CHUNK 64

typedef __bf16 bf16x8 __attribute__((ext_vector_type(8)));
typedef float f32x4 __attribute__((ext_vector_type(4)));
typedef unsigned short u16x8 __attribute__((ext_vector_type(8)));

static __device__ __forceinline__ unsigned short f2bf(float f) {
    unsigned int u = __float_as_uint(f);
    return (unsigned short)((u + 0x7fffu + ((u >> 16) & 1u)) >> 16);
}
static __device__ __forceinline__ float ubf(unsigned short u) {
    return __uint_as_float((unsigned int)u << 16);
}

// ---------------- convert x (fp32 -> bf16), 8 elems/thread ----------------
__global__ void k_convert_x(const float* __restrict__ x, unsigned short* __restrict__ xb) {
    int i = blockIdx.x * 256 + threadIdx.x;
    const float4* p = (const float4*)x;
    float4 v0 = p[2*i], v1 = p[2*i+1];
    u16x8 r;
    r[0] = f2bf(v0.x); r[1] = f2bf(v0.y); r[2] = f2bf(v0.z); r[3] = f2bf(v0.w);
    r[4] = f2bf(v1.x); r[5] = f2bf(v1.y); r[6] = f2bf(v1.z); r[7] = f2bf(v1.w);
    *(u16x8*)(xb + (size_t)i * 8) = r;
}

// ---------------- transpose + convert W: wt[g][n][k] = W_g[k][n] ----------
__global__ void k_transpose_w(const float* __restrict__ Wf, const float* __restrict__ Wi,
                              const float* __restrict__ Wb, unsigned short* __restrict__ wt) {
    __shared__ float tile[32][33];
    int g = blockIdx.z;
    const float* W = (g == 0) ? Wf : (g == 1) ? Wi : Wb;
    int n0 = blockIdx.x * 32, k0 = blockIdx.y * 32;
    int tx = threadIdx.x, ty = threadIdx.y;   // 32 x 8
    for (int j = 0; j < 4; ++j)
        tile[ty + j*8][tx] = W[(size_t)(k0 + ty + j*8) * D_MODEL + n0 + tx];
    __syncthreads();
    for (int j = 0; j < 4; ++j) {
        int n = n0 + ty + j*8;
        wt[(size_t)g * D_MODEL * D_MODEL + (size_t)n * D_MODEL + k0 + tx] = f2bf(tile[tx][ty + j*8]);
    }
}

// ---------------- fused 3-gate GEMM: 2 blocks/CU x 8 waves = 4 waves/SIMD -
// Round-11 structure (best: 135.7us) with doubled waves/block for latency
// hiding: 512 thr, per-wave 64x16 per gate (acc 48 regs -> <=128 total,
// launch_bounds(512,4)). 40 KiB tile dbuf = 80 KiB -> 2 blocks/CU.
// STAGE-at-top + single __syncthreads; compiler schedules lgkm interleave.
#define GL16(gp, lp) \
    __builtin_amdgcn_global_load_lds((const __attribute__((address_space(1))) void*)(gp), \
                                     (__attribute__((address_space(3))) void*)(lp), 16, 0, 0)

__launch_bounds__(512, 4)
__global__ void k_gemm_gates(const unsigned short* __restrict__ xb, const unsigned short* __restrict__ wt,
                             const float* __restrict__ bfv, const float* __restrict__ biv,
                             const float* __restrict__ bbv,
                             unsigned int* __restrict__ fbg_out,
                             float* __restrict__ Ac, float* __restrict__ Bc) {
    extern __shared__ char smem[];
    const int tid  = threadIdx.x;
    const int wave = tid >> 6;            // 0..7
    const int lane = tid & 63;
    const int lr = lane & 15, lg = lane >> 4;
    // XCD-aware bijective swizzle (2048 blocks % 8 == 0)
    const int bid = blockIdx.x;
    const int swz = (bid & 7) * 256 + (bid >> 3);
    const int mb = swz >> 4;              // 0..127
    const int nb = swz & 15;              // 0..15
    const int m0 = mb * BM;
    const int n0 = nb * BNG;
    const int wr = wave >> 2;             // 0..1 -> rows wr*64
    const int wc = wave & 3;              // 0..3 -> cols wc*16 per gate
    const int wrow = wr * 64;
    const int wcol = wc * 16;

    // ---- staging: 5 GL16 issues x 512 thr x 16B = 40 KiB/tile ------------
    const int srow = tid >> 3;                               // 0..63, srow&7 == (tid>>3)&7
    const int scb  = ((tid & 7) * 16) ^ ((srow & 7) << 4);   // inverse-swizzled src col
    const unsigned short* sA  = xb + (size_t)(m0 + srow) * D_MODEL + (scb >> 1);
    const unsigned short* sB0 = wt + 0ull*D_MODEL*D_MODEL + (size_t)(n0 + srow) * D_MODEL + (scb >> 1);
    const unsigned short* sB1 = wt + 1ull*D_MODEL*D_MODEL + (size_t)(n0 + srow) * D_MODEL + (scb >> 1);
    const unsigned short* sB2 = wt + 2ull*D_MODEL*D_MODEL + (size_t)(n0 + srow) * D_MODEL + (scb >> 1);

#define STAGE(db) do { \
        char* _d = smem + (db)*TILE_BYTES + wave*1024; \
        GL16(sA,               _d + 0*8192); \
        GL16(sA + 64*D_MODEL,  _d + 1*8192); \
        char* _e = _d + XS_BYTES; \
        GL16(sB0, _e + 0*8192); \
        GL16(sB1, _e + 1*8192); \
        GL16(sB2, _e + 2*8192); \
        sA += BK; sB0 += BK; sB1 += BK; sB2 += BK; \
    } while (0)

    f32x4 acc[3][4] = {};
    const int sxor = (lr & 7) << 4;   // read-side swizzle (row&7 == lr&7)

    STAGE(0);
    __syncthreads();

    for (int kt = 0; kt < NKT; ++kt) {
        if (kt + 1 < NKT) STAGE((kt + 1) & 1);
        const char* tb = smem + (kt & 1) * TILE_BYTES;
        #pragma unroll
        for (int kk = 0; kk < 2; ++kk) {
            const int ko = (kk*64 + lg*16) ^ sxor;
            const int bro = (wcol + lr)*128 + ko;
            bf16x8 bw0 = *(const bf16x8*)(tb + XS_BYTES + 0*WG_BYTES + bro);
            bf16x8 bw1 = *(const bf16x8*)(tb + XS_BYTES + 1*WG_BYTES + bro);
            bf16x8 bw2 = *(const bf16x8*)(tb + XS_BYTES + 2*WG_BYTES + bro);
            bf16x8 af[4];
            #pragma unroll
            for (int mi = 0; mi < 4; ++mi)
                af[mi] = *(const bf16x8*)(tb + (wrow + mi*16 + lr)*128 + ko);
            #pragma unroll
            for (int mi = 0; mi < 4; ++mi) {
                acc[0][mi] = __builtin_amdgcn_mfma_f32_16x16x32_bf16(af[mi], bw0, acc[0][mi], 0,0,0);
                acc[1][mi] = __builtin_amdgcn_mfma_f32_16x16x32_bf16(af[mi], bw1, acc[1][mi], 0,0,0);
                acc[2][mi] = __builtin_amdgcn_mfma_f32_16x16x32_bf16(af[mi], bw2, acc[2][mi], 0,0,0);
            }
        }
        __syncthreads();   // drains stage; next iter overwrites other buffer
    }

    // ---- epilogue: gates -> packed u32 (f | bg<<16) + chunk aggregates ---
    // C/D: col = lane&15, row = (lane>>4)*4 + reg. Wave's 64 rows = one
    // chunk; time idx = mi*16 + lg*4 + r. (round-8/11-verified tree)
    {
        const int col = n0 + wcol + lr;
        const float vbf = bfv[col], vbi = biv[col], vbb = bbv[col];
        float qA[4], qB[4];
        #pragma unroll
        for (int mi = 0; mi < 4; ++mi) {
            float Ap = 1.0f, Bp = 0.0f;
            #pragma unroll
            for (int r = 0; r < 4; ++r) {
                const int row = m0 + wrow + mi*16 + lg*4 + r;
                const float zf = acc[0][mi][r] + vbf;
                const float zi = acc[1][mi][r] + vbi;
                const float zb = (acc[2][mi][r] + vbb) * 0.03125f;  // /sqrt(1024)
                const float fg = 1.0f / (1.0f + __expf(-zf));
                const float ig = 1.0f / (1.0f + __expf(-zi));
                const unsigned short fu  = f2bf(fg);
                const unsigned short bgu = f2bf(ig * zb);
                const float a_r  = 1.0f - ubf(fu);    // rounded values so
                const float bg_r = ubf(bgu);          // aggregates match apply
                fbg_out[(size_t)row * D_MODEL + col] =
                    (unsigned int)fu | ((unsigned int)bgu << 16);
                Bp = fmaf(a_r, Bp, bg_r);   // time order: r ascending
                Ap *= a_r;
            }
            qA[mi] = Ap; qB[mi] = Bp;
        }
        // ordered 4-lane (lg) tree over 16-row quarters, serial compose
        float CA = 1.0f, CB = 0.0f;
        #pragma unroll
        for (int q = 0; q < 4; ++q) {
            float A = qA[q], B = qB[q];
            float Ao = __shfl_xor(A, 16), Bo = __shfl_xor(B, 16);
            float B1 = (lg & 1) ? fmaf(A, Bo, B) : fmaf(Ao, B, Bo);
            float A1 = A * Ao;
            Ao = __shfl_xor(A1, 32); Bo = __shfl_xor(B1, 32);
            float B2 = (lg & 2) ? fmaf(A1, Bo, B1) : fmaf(Ao, B1, Bo);
            float A2 = A1 * Ao;
            CB = fmaf(A2, CB, B2);
            CA = CA * A2;
        }
        if (lg == 0) {
            const int chG = mb * 2 + wr;     // global chunk id
            Ac[(size_t)chG * D_MODEL + col] = CA;
            Bc[(size_t)chG * D_MODEL + col] = CB;
        }
    }
#undef STAGE
}

// ---------------- scan pass 2: exclusive prefix over chunks ---------------
__global__ void k_chunk_prefix(const float* __restrict__ Ac, const float* __restrict__ Bc,
                               float* __restrict__ H) {
    const int d = (blockIdx.x & 3) * 256 + threadIdx.x;
    const int b = blockIdx.x >> 2;
    float h = 0.0f;
    for (int c = 0; c < NCHUNK; ++c) {
        const size_t o = ((size_t)b * NCHUNK + c) * D_MODEL + d;
        H[o] = h;
        h = fmaf(Ac[o], h, Bc[o]);
    }
}

// ---------------- scan pass 3: apply (packed u32 in, fp32 h out) ----------
__global__ void k_apply(const unsigned int* __restrict__ fbg,
                        const float* __restrict__ H, float* __restrict__ out) {
    const int d0 = (blockIdx.x & 1) * 512 + threadIdx.x * 2;
    const int c = (blockIdx.x >> 1) & 63;
    const int b = blockIdx.x >> 7;
    const size_t base = ((size_t)b * SEQ + (size_t)c * CHUNK) * D_MODEL + d0;
    const size_t hoff = ((size_t)b * NCHUNK + c) * D_MODEL + d0;
    float h0 = H[hoff], h1 = H[hoff + 1];
    for (int t = 0; t < CHUNK; ++t) {
        const size_t o = base + (size_t)t * D_MODEL;
        const uint2 v = *(const uint2*)(fbg + o);
        const float a0 = 1.0f - __uint_as_float(v.x << 16);
        const float b0 = __uint_as_float(v.x & 0xffff0000u);
        const float a1 = 1.0f - __uint_as_float(v.y << 16);
        const float b1 = __uint_as_float(v.y & 0xffff0000u);
        h0 = fmaf(a0, h0, b0);
        h1 = fmaf(a1, h1, b1);
        *(float2*)(out + o) = make_float2(h0, h1);
    }
}

extern "C" void kernel_launch(void* const* d_in, const int* in_sizes, int n_in,
                              void* d_out, int out_size, void* d_ws, size_t ws_size,
                              hipStream_t stream) {
    const float* x   = (const float*)d_in[0];
    const float* Wf  = (const float*)d_in[1];
    const float* bfv = (const float*)d_in[2];
    const float* Wi  = (const float*)d_in[3];
    const float* biv = (const float*)d_in[4];
    const float* Wb  = (const float*)d_in[5];
    const float* bbv = (const float*)d_in[6];
    float* out = (float*)d_out;

    char* ws = (char*)d_ws;
    unsigned int*   fbg   = (unsigned int*)ws;                      // 0..64 MiB
    unsigned short* xb    = (unsigned short*)(ws + (64ull << 20));  // 64..96 MiB
    unsigned short* wt    = (unsigned short*)(ws + (96ull << 20));  // 96..102 MiB
    float* Ac = (float*)(ws + (102ull << 20));
    float* Bc = (float*)(ws + (103ull << 20));
    float* Hb = (float*)(ws + (64ull << 20));   // reuse xb region after GEMM

    hipFuncSetAttribute((const void*)k_gemm_gates,
                        hipFuncAttributeMaxDynamicSharedMemorySize, SMEM_BYTES);

    hipLaunchKernelGGL(k_convert_x, dim3((M_TOT * D_MODEL / 8) / 256), dim3(256), 0, stream, x, xb);
    hipLaunchKernelGGL(k_transpose_w, dim3(32, 32, 3), dim3(32, 8), 0, stream, Wf, Wi, Wb, wt);
    hipLaunchKernelGGL(k_gemm_gates, dim3((M_TOT / BM) * (D_MODEL / BNG)), dim3(512), SMEM_BYTES, stream,
                       xb, wt, bfv, biv, bbv, fbg, Ac, Bc);
    hipLaunchKernelGGL(k_chunk_prefix, dim3(BATCH * (D_MODEL / 256)), dim3(256), 0, stream,
                       Ac, Bc, Hb);
    hipLaunchKernelGGL(k_apply, dim3(BATCH * NCHUNK * 2), dim3(256), 0, stream,
                       fbg, Hb, out);
}